// Round 9
// baseline (87.441 us; speedup 1.0000x reference)
//
#include <hip/hip_runtime.h>

#define NN 8192
#define FD 128
#define BK 128     // f32 K per step
#define NRING 4

typedef float f32x4 __attribute__((ext_vector_type(4)));
typedef short short8 __attribute__((ext_vector_type(8)));
typedef unsigned short ushort4v __attribute__((ext_vector_type(4)));
typedef unsigned short ushort8v __attribute__((ext_vector_type(8)));
typedef unsigned int uint4v __attribute__((ext_vector_type(4)));

__device__ __forceinline__ unsigned short f2bf(float f) {
  unsigned int u = __builtin_bit_cast(unsigned int, f);
  u += 0x7fffu + ((u >> 16) & 1u);   // round-to-nearest-even
  return (unsigned short)(u >> 16);
}
__device__ __forceinline__ float bf2f(unsigned short h) {
  unsigned int u = ((unsigned int)h) << 16;
  return __builtin_bit_cast(float, u);
}

// -------- Kernel 1: xk = x@kern (bf16), emitted as MFMA B-fragments + row-major
__global__ __launch_bounds__(256) void xk_kernel(
    const float* __restrict__ x, const float* __restrict__ kern,
    unsigned short* __restrict__ bfrag, unsigned short* __restrict__ xk_rm) {
  __shared__ __align__(16) unsigned short kl[FD * FD];
  __shared__ __align__(16) float xl[16 * FD];
  const int t = threadIdx.x;
  const int row0 = blockIdx.x * 16;

  #pragma unroll
  for (int j = 0; j < 16; ++j) {
    int idx = (j * 256 + t) * 4;
    f32x4 kv = *(const f32x4*)&kern[idx];
    ushort4v kw;
    #pragma unroll
    for (int q = 0; q < 4; ++q) kw[q] = f2bf(kv[q]);
    *(ushort4v*)&kl[idx] = kw;
  }
  #pragma unroll
  for (int j = 0; j < 2; ++j) {
    int idx = (j * 256 + t) * 4;
    *(f32x4*)&xl[idx] = *(const f32x4*)&x[(size_t)row0 * FD + idx];
  }
  __syncthreads();

  const int r0 = (t >> 5) * 2;
  const int c0 = (t & 31) * 4;
  float acc[2][4] = {};
  #pragma unroll 4
  for (int k = 0; k < FD; ++k) {
    ushort4v kq = *(const ushort4v*)&kl[k * FD + c0];
    float kv[4];
    #pragma unroll
    for (int q = 0; q < 4; ++q) kv[q] = bf2f(kq[q]);
    float x0 = xl[r0 * FD + k];
    float x1 = xl[(r0 + 1) * FD + k];
    #pragma unroll
    for (int q = 0; q < 4; ++q) {
      acc[0][q] += x0 * kv[q];
      acc[1][q] += x1 * kv[q];
    }
  }
  #pragma unroll
  for (int i = 0; i < 2; ++i) {
    const int r = row0 + r0 + i;
    const int kt = r >> 5;
    const int lhi = ((r >> 3) & 3) * 16;
    const int j = r & 7;
    ushort4v ow;
    #pragma unroll
    for (int q = 0; q < 4; ++q) {
      const int c = c0 + q;
      unsigned short bv = f2bf(acc[i][q]);
      ow[q] = bv;
      bfrag[(((size_t)kt * 8 + (c >> 4)) * 64 + (lhi + (c & 15))) * 8 + j] = bv;
    }
    *(ushort4v*)&xk_rm[(size_t)r * FD + c0] = ow;
  }
}

// -------- Kernel 2: DMA-ring split-K MFMA (global_load_lds + counted vmcnt) --
#define DMA_A(stp, buf)                                                       \
  do {                                                                        \
    _Pragma("unroll") for (int c = 0; c < 4; ++c) {                           \
      const float* g = ag[c] + (size_t)(stp) * BK;                            \
      __builtin_amdgcn_global_load_lds(                                       \
          (const __attribute__((address_space(1))) void*)g,                   \
          (__attribute__((address_space(3))) void*)                           \
              &ring[buf][(w * 4 + c) * 256],                                  \
          16, 0, 0);                                                          \
    }                                                                         \
  } while (0)

#define LOAD_B(stp, Bf)                                                       \
  do {                                                                        \
    const int ktg = kt0 + (stp) * 4;                                          \
    _Pragma("unroll") for (int kk = 0; kk < 4; ++kk)                          \
      _Pragma("unroll") for (int ci = 0; ci < 2; ++ci)                        \
        Bf[kk * 2 + ci] = *(const ushort8v*)(bp +                             \
            (((size_t)(ktg + kk) * 8 + (w * 2 + ci)) << 9));                  \
  } while (0)

#define WAITBAR()                                                             \
  do {                                                                        \
    asm volatile("s_waitcnt vmcnt(12)" ::: "memory");                         \
    __builtin_amdgcn_sched_barrier(0);                                        \
    __builtin_amdgcn_s_barrier();                                             \
    __builtin_amdgcn_sched_barrier(0);                                        \
  } while (0)

#define CONSUME(buf, Bf)                                                      \
  do {                                                                        \
    const float* sb = &ring[buf][0];                                          \
    _Pragma("unroll") for (int kk = 0; kk < 4; ++kk) {                        \
      short8 aF[2];                                                           \
      _Pragma("unroll") for (int mf = 0; mf < 2; ++mf) {                      \
        const int row = (l & 15) + 16 * mf;                                   \
        const int u0 = (l >> 4) * 2 + kk * 8;                                 \
        f32x4 lo = *(const f32x4*)&sb[row * BK + ((u0 ^ (row & 7)) * 4)];     \
        f32x4 hi = *(const f32x4*)&sb[row * BK + (((u0 + 1) ^ (row & 7)) * 4)];\
        unsigned int w0, w1, w2, w3;                                          \
        asm("v_cvt_pk_bf16_f32 %0, %1, %2" : "=v"(w0) : "v"(lo[0]), "v"(lo[1]));\
        asm("v_cvt_pk_bf16_f32 %0, %1, %2" : "=v"(w1) : "v"(lo[2]), "v"(lo[3]));\
        asm("v_cvt_pk_bf16_f32 %0, %1, %2" : "=v"(w2) : "v"(hi[0]), "v"(hi[1]));\
        asm("v_cvt_pk_bf16_f32 %0, %1, %2" : "=v"(w3) : "v"(hi[2]), "v"(hi[3]));\
        uint4v uw = {w0, w1, w2, w3};                                         \
        aF[mf] = __builtin_bit_cast(short8, uw);                              \
        if (kk == w)                                                          \
          rs[mf] += lo[0] + lo[1] + lo[2] + lo[3] +                           \
                    hi[0] + hi[1] + hi[2] + hi[3];                            \
      }                                                                       \
      _Pragma("unroll") for (int mf = 0; mf < 2; ++mf)                        \
        _Pragma("unroll") for (int ci = 0; ci < 2; ++ci)                      \
          acc[mf][ci] = __builtin_amdgcn_mfma_f32_16x16x32_bf16(              \
              aF[mf], Bf[kk * 2 + ci], acc[mf][ci], 0, 0, 0);                 \
    }                                                                         \
  } while (0)

template <int S>
__global__ __launch_bounds__(256, 2) void gcn_mm(
    const float* __restrict__ adj, const unsigned short* __restrict__ bfrag,
    unsigned short* __restrict__ parts, float* __restrict__ rowpart) {
  constexpr int KW = NN / S;
  constexpr int NS = KW / BK;       // 8 at S=8
  static_assert(NS >= 4 && (NS % 2) == 0, "ring needs NS>=4 even");
  __shared__ float ring[NRING][32 * BK];   // 64 KB
  __shared__ float rsx[4][2][16];

  const int t = threadIdx.x;
  const int l = t & 63;
  const int w = t >> 6;
  const int b = blockIdx.x;
  const int s = b & (S - 1);                 // K-slot == XCD (round-robin)
  const int row0 = (b / S) * 32;
  const int kbase = s * KW;
  const int kt0 = s * (KW / 32);

  // DMA source: wave w stages chunks 4w..4w+3 (rows 8w..8w+7), 1 KB/instr.
  // chunk c: lane l -> row = 8w + 2c + (l>>5); slot p = l&31; global u = p^(row&7)
  const float* ag[4];
  #pragma unroll
  for (int c = 0; c < 4; ++c) {
    const int row = 8 * w + 2 * c + (l >> 5);
    const int u = (l & 31) ^ (row & 7);
    ag[c] = adj + (size_t)(row0 + row) * NN + kbase + u * 4;
  }
  const unsigned short* bp = bfrag + (size_t)l * 8;

  ushort8v BfA[8], BfB[8];
  f32x4 acc[2][2] = {};
  float rs[2] = {0.f, 0.f};

  // prologue: 3 tiles in flight + B(0)
  DMA_A(0, 0);
  DMA_A(1, 1);
  DMA_A(2, 2);
  LOAD_B(0, BfA);

  for (int j = 0; j < NS; j += 2) {
    // even sub-iter: consume buffer j (BfA)
    LOAD_B((j + 1 < NS ? j + 1 : NS - 1), BfB);
    WAITBAR();
    if (j + 3 < NS) DMA_A(j + 3, (j + 3) & 3);
    __builtin_amdgcn_sched_barrier(0);
    CONSUME(j & 3, BfA);
    // odd sub-iter: consume buffer j+1 (BfB)
    LOAD_B((j + 2 < NS ? j + 2 : NS - 1), BfA);
    WAITBAR();
    if (j + 4 < NS) DMA_A(j + 4, (j + 4) & 3);
    __builtin_amdgcn_sched_barrier(0);
    CONSUME((j + 1) & 3, BfB);
  }

  // ---- rowsum: lane partials cover (row, kk==w slice); reduce k-lane groups
  #pragma unroll
  for (int mf = 0; mf < 2; ++mf) {
    rs[mf] += __shfl_xor(rs[mf], 16);
    rs[mf] += __shfl_xor(rs[mf], 32);
  }
  if (l < 16) {
    rsx[w][0][l] = rs[0];
    rsx[w][1][l] = rs[1];
  }
  __syncthreads();
  if (t < 32) {
    float tot = rsx[0][t >> 4][t & 15] + rsx[1][t >> 4][t & 15] +
                rsx[2][t >> 4][t & 15] + rsx[3][t >> 4][t & 15];
    rowpart[(size_t)s * NN + row0 + t] = tot;
  }

  // ---- store bf16 partial tile: C/D col = l&15, row = (l>>4)*4 + j ----
  unsigned short* pp = parts + ((size_t)s * NN + row0) * FD + w * 32;
  #pragma unroll
  for (int mf = 0; mf < 2; ++mf)
    #pragma unroll
    for (int ci = 0; ci < 2; ++ci)
      #pragma unroll
      for (int jj = 0; jj < 4; ++jj) {
        const int r = mf * 16 + ((l >> 4) << 2) + jj;
        pp[(size_t)r * FD + ci * 16 + (l & 15)] = f2bf(acc[mf][ci][jj]);
      }
}

// -------- Kernel 3: reduce S partials + epilogue ---------------------------
__global__ __launch_bounds__(256) void gcn_fin(
    const unsigned short* __restrict__ parts, const float* __restrict__ rowpart,
    const unsigned short* __restrict__ xk_rm, const float* __restrict__ beta,
    const float* __restrict__ bias, float* __restrict__ out, int S) {
  const int t = threadIdx.x;
  const int r = blockIdx.x * 16 + (t >> 4);
  const int c0 = (t & 15) * 8;

  float rsum = 0.f;
  for (int s = 0; s < S; ++s) rsum += rowpart[(size_t)s * NN + r];
  const float bt = beta[r];
  const float inv = 1.0f / (rsum + bt);

  float a[8] = {0.f, 0.f, 0.f, 0.f, 0.f, 0.f, 0.f, 0.f};
  for (int s = 0; s < S; ++s) {
    ushort8v pv = *(const ushort8v*)&parts[((size_t)s * NN + r) * FD + c0];
    #pragma unroll
    for (int q = 0; q < 8; ++q) a[q] += bf2f(pv[q]);
  }
  ushort8v xv = *(const ushort8v*)&xk_rm[(size_t)r * FD + c0];
  f32x4 o0, o1;
  #pragma unroll
  for (int q = 0; q < 4; ++q) {
    o0[q] = (a[q] + bt * bf2f(xv[q])) * inv + bias[c0 + q];
    o1[q] = (a[4 + q] + bt * bf2f(xv[4 + q])) * inv + bias[c0 + 4 + q];
  }
  *(f32x4*)&out[(size_t)r * FD + c0] = o0;
  *(f32x4*)&out[(size_t)r * FD + c0 + 4] = o1;
}

extern "C" void kernel_launch(void* const* d_in, const int* in_sizes, int n_in,
                              void* d_out, int out_size, void* d_ws, size_t ws_size,
                              hipStream_t stream) {
  const float* x    = (const float*)d_in[0];
  const float* adj  = (const float*)d_in[1];
  const float* kern = (const float*)d_in[2];
  const float* bias = (const float*)d_in[3];
  const float* beta = (const float*)d_in[4];
  float* out = (float*)d_out;

  char* ws = (char*)d_ws;
  unsigned short* bfrag = (unsigned short*)ws;                          // 2 MB
  unsigned short* xk_rm = (unsigned short*)(ws + (size_t)NN * FD * 2);  // 2 MB
  const size_t off_rowpart = (size_t)NN * FD * 4;
  float* rowpart = (float*)(ws + off_rowpart);                          // 256 KB
  const size_t off_parts = off_rowpart + (size_t)8 * NN * 4;
  unsigned short* parts = (unsigned short*)(ws + off_parts);            // 16 MB @ S=8

  int S = 8;
  while (S > 1 && off_parts + (size_t)S * NN * FD * 2 > ws_size) S >>= 1;

  hipLaunchKernelGGL(xk_kernel, dim3(NN / 16), dim3(256), 0, stream,
                     x, kern, bfrag, xk_rm);

  dim3 blk(256);
  switch (S) {
    case 8: hipLaunchKernelGGL(gcn_mm<8>, dim3(256 * 8), blk, 0, stream, adj, bfrag, parts, rowpart); break;
    case 4: hipLaunchKernelGGL(gcn_mm<4>, dim3(256 * 4), blk, 0, stream, adj, bfrag, parts, rowpart); break;
    case 2: hipLaunchKernelGGL(gcn_mm<2>, dim3(256 * 2), blk, 0, stream, adj, bfrag, parts, rowpart); break;
    default: hipLaunchKernelGGL(gcn_mm<1>, dim3(256), blk, 0, stream, adj, bfrag, parts, rowpart); break;
  }

  hipLaunchKernelGGL(gcn_fin, dim3(NN / 16), dim3(256), 0, stream,
                     parts, rowpart, xk_rm, beta, bias, out, S);
}